// Round 18
// baseline (44.265 us; speedup 1.0000x reference)
//
#include <hip/hip_runtime.h>

constexpr int kNodes = 10000;
constexpr int kEdges = 640000;
constexpr int kD = 128;

typedef unsigned int   u32;
typedef unsigned short u16;

constexpr int kNB     = 1250;                 // buckets of 8 nodes (10000/8)
constexpr int kNCHUNK = 250;                  // partition blocks
constexpr int kCHUNK  = 2560;                 // edges per partition block
constexpr int kCap    = 16;                   // per-(blk,bkt) sub-run capacity (mean 2.05)
constexpr int kRawMax = 1024;                 // per-bucket edge cap (mean 512, +22 sigma)
constexpr int kGemmBlocks = kNodes / 16;      // 625 (16 rows per block)

__device__ inline u16 f2bf(float x) {         // round-to-nearest-even
    u32 u = __float_as_uint(x);
    u32 r = u + 0x7FFF + ((u >> 16) & 1);
    return (u16)(r >> 16);
}
__device__ inline float bf_lo(u32 v) { return __uint_as_float(v << 16); }
__device__ inline float bf_hi(u32 v) { return __uint_as_float(v & 0xFFFF0000u); }

// ---------------------------------------------------------------------------
// Path A (fallback): direct atomic scatter-add + fp32 GEMM
// ---------------------------------------------------------------------------
__global__ void scatter_add_kernel(const float* __restrict__ feature,
                                   const int* __restrict__ src,
                                   const int* __restrict__ dst,
                                   float* __restrict__ h) {
    long long tid = (long long)blockIdx.x * blockDim.x + threadIdx.x;
    int e    = (int)(tid >> 5);
    int lane = (int)(tid & 31);
    if (e >= kEdges) return;
    int s = src[e];
    int d = dst[e];
    const float4 v = *reinterpret_cast<const float4*>(feature + (size_t)s * kD + lane * 4);
    float* hp = h + (size_t)d * kD + lane * 4;
    atomicAdd(hp + 0, v.x);
    atomicAdd(hp + 1, v.y);
    atomicAdd(hp + 2, v.z);
    atomicAdd(hp + 3, v.w);
}

__global__ __launch_bounds__(256)
void gemm_bias_kernel(const float* __restrict__ h,
                      const float* __restrict__ W,
                      const float* __restrict__ b,
                      float* __restrict__ out) {
    __shared__ float Wl[kD * kD];
    int t = threadIdx.x;
#pragma unroll
    for (int i = 0; i < 16; ++i) {
        int idx = t + i * 256;
        reinterpret_cast<float4*>(Wl)[idx] = reinterpret_cast<const float4*>(W)[idx];
    }
    __syncthreads();
    int row = blockIdx.x * 8 + (t >> 5);
    int j0  = (t & 31) * 4;
    if (row >= kNodes) return;
    const float* hrow = h + (size_t)row * kD;
    float4 acc = make_float4(0.f, 0.f, 0.f, 0.f);
#pragma unroll 4
    for (int k = 0; k < kD; k += 4) {
        float4 hv4 = *reinterpret_cast<const float4*>(hrow + k);
        const float* wk = Wl + (size_t)k * kD + j0;
        float4 w0 = *reinterpret_cast<const float4*>(wk + 0 * kD);
        float4 w1 = *reinterpret_cast<const float4*>(wk + 1 * kD);
        float4 w2 = *reinterpret_cast<const float4*>(wk + 2 * kD);
        float4 w3 = *reinterpret_cast<const float4*>(wk + 3 * kD);
        acc.x += hv4.x * w0.x + hv4.y * w1.x + hv4.z * w2.x + hv4.w * w3.x;
        acc.y += hv4.x * w0.y + hv4.y * w1.y + hv4.z * w2.y + hv4.w * w3.y;
        acc.z += hv4.x * w0.z + hv4.y * w1.z + hv4.z * w2.z + hv4.w * w3.z;
        acc.w += hv4.x * w0.w + hv4.y * w1.w + hv4.z * w2.w + hv4.w * w3.w;
    }
    const float4 bb = *reinterpret_cast<const float4*>(b + j0);
    acc.x += bb.x; acc.y += bb.y; acc.z += bb.z; acc.w += bb.w;
    *reinterpret_cast<float4*>(out + (size_t)row * kD + j0) = acc;
}

// ---------------------------------------------------------------------------
// Path B, phase 1 (fused): blocks [0,250) partition edges into
// per-(block,bucket) sub-runs (8-node buckets, cap 16); blocks [250,875)
// compute 16 rows of FW = feature @ W. NEW: W staged as bf16 in a single
// 32 KB stage (half the LDS W-read bytes, one stage barrier). 5 blocks/CU.
// ---------------------------------------------------------------------------
__global__ __launch_bounds__(256)
void phase1_kernel(const float* __restrict__ feature,
                   const float* __restrict__ W,
                   const int* __restrict__ src,
                   const int* __restrict__ dst,
                   u16* __restrict__ FW,
                   int* __restrict__ cnts,     // [kNCHUNK][kNB]
                   u32* __restrict__ csr) {    // [kNCHUNK][kNB][kCap]
    __shared__ u16 Wl[kD * kD];     // 32 KB (bf16 W); partition reuses 5 KB
    int t = threadIdx.x;

    if (blockIdx.x < kNCHUNK) {
        // ----- partition branch: single pass, LDS cursors only -----
        int* cur = reinterpret_cast<int*>(Wl);         // [kNB], 5 KB
        int blk  = blockIdx.x;

        for (int i = t; i < kNB; i += 256) cur[i] = 0;
        __syncthreads();

        int base = blk * kCHUNK;
        u32* myCsr = csr + (size_t)blk * kNB * kCap;
#pragma unroll
        for (int j = 0; j < 10; ++j) {
            int e = base + t + j * 256;
            int d = dst[e];
            int s = src[e];
            int bkt = d >> 3;
            int pos = atomicAdd(&cur[bkt], 1);
            if (pos < kCap)
                myCsr[bkt * kCap + pos] = ((u32)d << 16) | (u32)s;
        }
        __syncthreads();
        for (int i = t; i < kNB; i += 256) {
            int c = cur[i];
            cnts[blk * kNB + i] = c < kCap ? c : kCap;
        }
    } else {
        // ----- GEMM branch: 16 rows, 2 rows/thread, bf16 W single-stage -----
        // stage all 128x128 W as bf16: 4096 float4 -> 4096 uint2
#pragma unroll
        for (int i = 0; i < 16; ++i) {
            int idx = t + i * 256;
            float4 w4 = reinterpret_cast<const float4*>(W)[idx];
            u32 lo = (u32)f2bf(w4.x) | ((u32)f2bf(w4.y) << 16);
            u32 hi = (u32)f2bf(w4.z) | ((u32)f2bf(w4.w) << 16);
            reinterpret_cast<uint2*>(Wl)[idx] = make_uint2(lo, hi);
        }
        __syncthreads();

        int rp   = t >> 5;
        int j0   = (t & 31) * 4;
        int row0 = (blockIdx.x - kNCHUNK) * 16 + rp * 2;
        const float* h0 = feature + (size_t)row0 * kD;
        const float* h1 = h0 + kD;

        float4 acc0 = make_float4(0.f, 0.f, 0.f, 0.f);
        float4 acc1 = make_float4(0.f, 0.f, 0.f, 0.f);
#pragma unroll 4
        for (int k = 0; k < kD; k += 4) {
            float4 a0 = *reinterpret_cast<const float4*>(h0 + k);
            float4 a1 = *reinterpret_cast<const float4*>(h1 + k);
            const u16* wk = Wl + (size_t)k * kD + j0;
            uint2 q0 = *reinterpret_cast<const uint2*>(wk + 0 * kD);
            uint2 q1 = *reinterpret_cast<const uint2*>(wk + 1 * kD);
            uint2 q2 = *reinterpret_cast<const uint2*>(wk + 2 * kD);
            uint2 q3 = *reinterpret_cast<const uint2*>(wk + 3 * kD);
            float w00 = bf_lo(q0.x), w01 = bf_hi(q0.x), w02 = bf_lo(q0.y), w03 = bf_hi(q0.y);
            float w10 = bf_lo(q1.x), w11 = bf_hi(q1.x), w12 = bf_lo(q1.y), w13 = bf_hi(q1.y);
            float w20 = bf_lo(q2.x), w21 = bf_hi(q2.x), w22 = bf_lo(q2.y), w23 = bf_hi(q2.y);
            float w30 = bf_lo(q3.x), w31 = bf_hi(q3.x), w32 = bf_lo(q3.y), w33 = bf_hi(q3.y);
            acc0.x += a0.x * w00 + a0.y * w10 + a0.z * w20 + a0.w * w30;
            acc0.y += a0.x * w01 + a0.y * w11 + a0.z * w21 + a0.w * w31;
            acc0.z += a0.x * w02 + a0.y * w12 + a0.z * w22 + a0.w * w32;
            acc0.w += a0.x * w03 + a0.y * w13 + a0.z * w23 + a0.w * w33;
            acc1.x += a1.x * w00 + a1.y * w10 + a1.z * w20 + a1.w * w30;
            acc1.y += a1.x * w01 + a1.y * w11 + a1.z * w21 + a1.w * w31;
            acc1.z += a1.x * w02 + a1.y * w12 + a1.z * w22 + a1.w * w32;
            acc1.w += a1.x * w03 + a1.y * w13 + a1.z * w23 + a1.w * w33;
        }

        u32 lo0 = (u32)f2bf(acc0.x) | ((u32)f2bf(acc0.y) << 16);
        u32 hi0 = (u32)f2bf(acc0.z) | ((u32)f2bf(acc0.w) << 16);
        u32 lo1 = (u32)f2bf(acc1.x) | ((u32)f2bf(acc1.y) << 16);
        u32 hi1 = (u32)f2bf(acc1.z) | ((u32)f2bf(acc1.w) << 16);
        *reinterpret_cast<uint2*>(FW + (size_t)row0 * kD + j0)       = make_uint2(lo0, hi0);
        *reinterpret_cast<uint2*>(FW + (size_t)(row0 + 1) * kD + j0) = make_uint2(lo1, hi1);
    }
}

// ---------------------------------------------------------------------------
// Path B, phase 2: one block per 8-node bucket (1250 blocks x 256 thr).
// (byte-identical to round 17)
// ---------------------------------------------------------------------------
__global__ __launch_bounds__(256)
void bucket_gather_kernel(const u16* __restrict__ FW,
                          const int* __restrict__ cnts,
                          const u32* __restrict__ csr,
                          const float* __restrict__ b,
                          float* __restrict__ out) {
    __shared__ u16 srt[kRawMax];
    __shared__ int cnt8[8], noff8[8], cur8[8];
    int t   = threadIdx.x;
    int bkt = blockIdx.x;

    int myLen = (t < kNCHUNK) ? cnts[t * kNB + bkt] : 0;
    if (t < 8) cnt8[t] = 0;

    uint4 rec[4];
    const u32* sr = csr + ((size_t)t * kNB + bkt) * kCap;
#pragma unroll
    for (int i = 0; i < 4; ++i) {
        if (i * 4 < myLen) rec[i] = *reinterpret_cast<const uint4*>(sr + i * 4);
    }
    __syncthreads();

#pragma unroll
    for (int i = 0; i < 4; ++i) {
        if (i * 4 < myLen) {
            atomicAdd(&cnt8[(rec[i].x >> 16) & 7], 1);
            if (i * 4 + 1 < myLen) atomicAdd(&cnt8[(rec[i].y >> 16) & 7], 1);
            if (i * 4 + 2 < myLen) atomicAdd(&cnt8[(rec[i].z >> 16) & 7], 1);
            if (i * 4 + 3 < myLen) atomicAdd(&cnt8[(rec[i].w >> 16) & 7], 1);
        }
    }
    __syncthreads();
    if (t == 0) {
        int r = 0;
#pragma unroll
        for (int i = 0; i < 8; ++i) { noff8[i] = r; cur8[i] = r; r += cnt8[i]; }
    }
    __syncthreads();

#pragma unroll
    for (int i = 0; i < 4; ++i) {
        if (i * 4 < myLen) {
            int p;
            p = atomicAdd(&cur8[(rec[i].x >> 16) & 7], 1);
            if (p < kRawMax) srt[p] = (u16)(rec[i].x & 0xFFFFu);
            if (i * 4 + 1 < myLen) {
                p = atomicAdd(&cur8[(rec[i].y >> 16) & 7], 1);
                if (p < kRawMax) srt[p] = (u16)(rec[i].y & 0xFFFFu);
            }
            if (i * 4 + 2 < myLen) {
                p = atomicAdd(&cur8[(rec[i].z >> 16) & 7], 1);
                if (p < kRawMax) srt[p] = (u16)(rec[i].z & 0xFFFFu);
            }
            if (i * 4 + 3 < myLen) {
                p = atomicAdd(&cur8[(rec[i].w >> 16) & 7], 1);
                if (p < kRawMax) srt[p] = (u16)(rec[i].w & 0xFFFFu);
            }
        }
    }
    __syncthreads();

    int wv     = t >> 6;
    int lane   = t & 63;
    int half   = lane >> 5;
    int lane32 = lane & 31;
    int nodeBase = bkt * 8;
    const float4 bb = *reinterpret_cast<const float4*>(b + lane32 * 4);

    {
        int nd   = wv * 2 + half;
        int node = nodeBase + nd;
        int s0 = noff8[nd];
        int e0 = s0 + cnt8[nd];
        if (e0 > kRawMax) e0 = kRawMax;
        float ax = 0.f, ay = 0.f, az = 0.f, aw = 0.f;
        int i = s0;
        for (; i + 8 <= e0; i += 8) {
            uint2 v[8];
#pragma unroll
            for (int u = 0; u < 8; ++u) {
                int s = (int)srt[i + u];
                v[u] = *reinterpret_cast<const uint2*>(FW + (size_t)s * kD + lane32 * 4);
            }
#pragma unroll
            for (int u = 0; u < 8; ++u) {
                ax += bf_lo(v[u].x); ay += bf_hi(v[u].x);
                az += bf_lo(v[u].y); aw += bf_hi(v[u].y);
            }
        }
        for (; i < e0; ++i) {
            int s = (int)srt[i];
            uint2 v = *reinterpret_cast<const uint2*>(FW + (size_t)s * kD + lane32 * 4);
            ax += bf_lo(v.x); ay += bf_hi(v.x);
            az += bf_lo(v.y); aw += bf_hi(v.y);
        }
        *reinterpret_cast<float4*>(out + (size_t)node * kD + lane32 * 4) =
            make_float4(ax + bb.x, ay + bb.y, az + bb.z, aw + bb.w);
    }
}

extern "C" void kernel_launch(void* const* d_in, const int* in_sizes, int n_in,
                              void* d_out, int out_size, void* d_ws, size_t ws_size,
                              hipStream_t stream) {
    const float* feature = (const float*)d_in[0];
    const int*   src     = (const int*)d_in[1];
    const int*   dst     = (const int*)d_in[2];
    const float* W       = (const float*)d_in[3];
    const float* b       = (const float*)d_in[4];
    float*       out     = (float*)d_out;

    // Workspace layout (Path B) — fully rewritten each call, no init needed
    char* ws = (char*)d_ws;
    size_t off = 0;
    u16* FW   = (u16*)(ws + off);  off += (size_t)kNodes * kD * sizeof(u16);
    int* cnts = (int*)(ws + off);  off += (size_t)kNCHUNK * kNB * sizeof(int);
    off = (off + 127) & ~(size_t)127;
    u32* csr  = (u32*)(ws + off);  off += (size_t)kNCHUNK * kNB * kCap * sizeof(u32);
    const size_t neededB = off;
    const size_t neededA = (size_t)kNodes * kD * sizeof(float);

    if (ws_size >= neededB) {
        phase1_kernel<<<kNCHUNK + kGemmBlocks, 256, 0, stream>>>(
            feature, W, src, dst, FW, cnts, csr);
        bucket_gather_kernel<<<kNB, 256, 0, stream>>>(FW, cnts, csr, b, out);
    } else if (ws_size >= neededA) {
        float* h = (float*)d_ws;
        hipMemsetAsync(h, 0, neededA, stream);
        long long total = (long long)kEdges * 32;
        int threads = 256;
        int blocks  = (int)((total + threads - 1) / threads);
        scatter_add_kernel<<<blocks, threads, 0, stream>>>(feature, src, dst, h);
        gemm_bias_kernel<<<(kNodes + 7) / 8, 256, 0, stream>>>(h, W, b, out);
    }
}

// Round 19
// 39.114 us; speedup vs baseline: 1.1317x; 1.1317x over previous
//
#include <hip/hip_runtime.h>

constexpr int kNodes = 10000;
constexpr int kEdges = 640000;
constexpr int kD = 128;

typedef unsigned int   u32;
typedef unsigned short u16;

constexpr int kNB     = 1250;                 // buckets of 8 nodes (10000/8)
constexpr int kNCHUNK = 250;                  // partition blocks
constexpr int kCHUNK  = 2560;                 // edges per partition block
constexpr int kCap    = 16;                   // per-(blk,bkt) sub-run capacity (mean 2.05)
constexpr int kRawMax = 1024;                 // per-bucket edge cap (mean 512, +22 sigma)
constexpr int kGemmBlocks = kNodes / 16;      // 625 (16 rows per block)

__device__ inline u16 f2bf(float x) {         // round-to-nearest-even
    u32 u = __float_as_uint(x);
    u32 r = u + 0x7FFF + ((u >> 16) & 1);
    return (u16)(r >> 16);
}
__device__ inline float bf_lo(u32 v) { return __uint_as_float(v << 16); }
__device__ inline float bf_hi(u32 v) { return __uint_as_float(v & 0xFFFF0000u); }

// ---------------------------------------------------------------------------
// Path A (fallback): direct atomic scatter-add + fp32 GEMM
// ---------------------------------------------------------------------------
__global__ void scatter_add_kernel(const float* __restrict__ feature,
                                   const int* __restrict__ src,
                                   const int* __restrict__ dst,
                                   float* __restrict__ h) {
    long long tid = (long long)blockIdx.x * blockDim.x + threadIdx.x;
    int e    = (int)(tid >> 5);
    int lane = (int)(tid & 31);
    if (e >= kEdges) return;
    int s = src[e];
    int d = dst[e];
    const float4 v = *reinterpret_cast<const float4*>(feature + (size_t)s * kD + lane * 4);
    float* hp = h + (size_t)d * kD + lane * 4;
    atomicAdd(hp + 0, v.x);
    atomicAdd(hp + 1, v.y);
    atomicAdd(hp + 2, v.z);
    atomicAdd(hp + 3, v.w);
}

__global__ __launch_bounds__(256)
void gemm_bias_kernel(const float* __restrict__ h,
                      const float* __restrict__ W,
                      const float* __restrict__ b,
                      float* __restrict__ out) {
    __shared__ float Wl[kD * kD];
    int t = threadIdx.x;
#pragma unroll
    for (int i = 0; i < 16; ++i) {
        int idx = t + i * 256;
        reinterpret_cast<float4*>(Wl)[idx] = reinterpret_cast<const float4*>(W)[idx];
    }
    __syncthreads();
    int row = blockIdx.x * 8 + (t >> 5);
    int j0  = (t & 31) * 4;
    if (row >= kNodes) return;
    const float* hrow = h + (size_t)row * kD;
    float4 acc = make_float4(0.f, 0.f, 0.f, 0.f);
#pragma unroll 4
    for (int k = 0; k < kD; k += 4) {
        float4 hv4 = *reinterpret_cast<const float4*>(hrow + k);
        const float* wk = Wl + (size_t)k * kD + j0;
        float4 w0 = *reinterpret_cast<const float4*>(wk + 0 * kD);
        float4 w1 = *reinterpret_cast<const float4*>(wk + 1 * kD);
        float4 w2 = *reinterpret_cast<const float4*>(wk + 2 * kD);
        float4 w3 = *reinterpret_cast<const float4*>(wk + 3 * kD);
        acc.x += hv4.x * w0.x + hv4.y * w1.x + hv4.z * w2.x + hv4.w * w3.x;
        acc.y += hv4.x * w0.y + hv4.y * w1.y + hv4.z * w2.y + hv4.w * w3.y;
        acc.z += hv4.x * w0.z + hv4.y * w1.z + hv4.z * w2.z + hv4.w * w3.z;
        acc.w += hv4.x * w0.w + hv4.y * w1.w + hv4.z * w2.w + hv4.w * w3.w;
    }
    const float4 bb = *reinterpret_cast<const float4*>(b + j0);
    acc.x += bb.x; acc.y += bb.y; acc.z += bb.z; acc.w += bb.w;
    *reinterpret_cast<float4*>(out + (size_t)row * kD + j0) = acc;
}

// ---------------------------------------------------------------------------
// Path B, phase 1 (fused): blocks [0,250) partition edges into
// per-(bucket,block) sub-runs — csr laid out [bkt][blk][kCap] so the gather
// reads it coalesced; each 64B line still written by exactly one block.
// Blocks [250,875): 16 rows of FW = feature @ W (bf16 out), fp32 W staged
// in TWO 32 KB halves (k-split) -> 5 blocks/CU, all co-resident.
// ---------------------------------------------------------------------------
__global__ __launch_bounds__(256)
void phase1_kernel(const float* __restrict__ feature,
                   const float* __restrict__ W,
                   const int* __restrict__ src,
                   const int* __restrict__ dst,
                   u16* __restrict__ FW,
                   int* __restrict__ cnts,     // [kNCHUNK][kNB]  (block-local writes)
                   u32* __restrict__ csr) {    // [kNB][kNCHUNK][kCap] (transposed)
    __shared__ float Wl[64 * kD];   // 32 KB; partition branch reuses 5 KB
    int t = threadIdx.x;

    if (blockIdx.x < kNCHUNK) {
        // ----- partition branch: single pass, LDS cursors only -----
        int* cur = reinterpret_cast<int*>(Wl);         // [kNB], 5 KB
        int blk  = blockIdx.x;

        for (int i = t; i < kNB; i += 256) cur[i] = 0;
        __syncthreads();

        int base = blk * kCHUNK;
#pragma unroll
        for (int j = 0; j < 10; ++j) {
            int e = base + t + j * 256;
            int d = dst[e];
            int s = src[e];
            int bkt = d >> 3;
            int pos = atomicAdd(&cur[bkt], 1);
            if (pos < kCap)
                csr[((size_t)bkt * kNCHUNK + blk) * kCap + pos] = ((u32)d << 16) | (u32)s;
        }
        __syncthreads();
        for (int i = t; i < kNB; i += 256) {
            int c = cur[i];
            cnts[blk * kNB + i] = c < kCap ? c : kCap;
        }
    } else {
        // ----- GEMM branch: 16 rows, 2 rows/thread, W in 2 half-stages -----
        int rp   = t >> 5;
        int j0   = (t & 31) * 4;
        int row0 = (blockIdx.x - kNCHUNK) * 16 + rp * 2;
        const float* h0 = feature + (size_t)row0 * kD;
        const float* h1 = h0 + kD;

        float4 acc0 = make_float4(0.f, 0.f, 0.f, 0.f);
        float4 acc1 = make_float4(0.f, 0.f, 0.f, 0.f);

        for (int kh = 0; kh < 2; ++kh) {
            const float4* Wsrc = reinterpret_cast<const float4*>(W + (size_t)kh * 64 * kD);
#pragma unroll
            for (int i = 0; i < 8; ++i) {
                int idx = t + i * 256;
                reinterpret_cast<float4*>(Wl)[idx] = Wsrc[idx];
            }
            __syncthreads();

            const float* ha0 = h0 + kh * 64;
            const float* ha1 = h1 + kh * 64;
#pragma unroll 4
            for (int k = 0; k < 64; k += 4) {
                float4 a0 = *reinterpret_cast<const float4*>(ha0 + k);
                float4 a1 = *reinterpret_cast<const float4*>(ha1 + k);
                const float* wk = Wl + (size_t)k * kD + j0;
                float4 w0 = *reinterpret_cast<const float4*>(wk + 0 * kD);
                float4 w1 = *reinterpret_cast<const float4*>(wk + 1 * kD);
                float4 w2 = *reinterpret_cast<const float4*>(wk + 2 * kD);
                float4 w3 = *reinterpret_cast<const float4*>(wk + 3 * kD);
                acc0.x += a0.x * w0.x + a0.y * w1.x + a0.z * w2.x + a0.w * w3.x;
                acc0.y += a0.x * w0.y + a0.y * w1.y + a0.z * w2.y + a0.w * w3.y;
                acc0.z += a0.x * w0.z + a0.y * w1.z + a0.z * w2.z + a0.w * w3.z;
                acc0.w += a0.x * w0.w + a0.y * w1.w + a0.z * w2.w + a0.w * w3.w;
                acc1.x += a1.x * w0.x + a1.y * w1.x + a1.z * w2.x + a1.w * w3.x;
                acc1.y += a1.x * w0.y + a1.y * w1.y + a1.z * w2.y + a1.w * w3.y;
                acc1.z += a1.x * w0.z + a1.y * w1.z + a1.z * w2.z + a1.w * w3.z;
                acc1.w += a1.x * w0.w + a1.y * w1.w + a1.z * w2.w + a1.w * w3.w;
            }
            if (kh == 0) __syncthreads();   // protect Wl before re-stage
        }

        u32 lo0 = (u32)f2bf(acc0.x) | ((u32)f2bf(acc0.y) << 16);
        u32 hi0 = (u32)f2bf(acc0.z) | ((u32)f2bf(acc0.w) << 16);
        u32 lo1 = (u32)f2bf(acc1.x) | ((u32)f2bf(acc1.y) << 16);
        u32 hi1 = (u32)f2bf(acc1.z) | ((u32)f2bf(acc1.w) << 16);
        *reinterpret_cast<uint2*>(FW + (size_t)row0 * kD + j0)       = make_uint2(lo0, hi0);
        *reinterpret_cast<uint2*>(FW + (size_t)(row0 + 1) * kD + j0) = make_uint2(lo1, hi1);
    }
}

// ---------------------------------------------------------------------------
// Path B, phase 2: one block per 8-node bucket (1250 blocks x 256 thr).
// csr now [bkt][blk][kCap]: thread t's 64B sub-run is line-consecutive with
// thread t+1's -> wave staging loads fully coalesced (4KB per wave).
// ---------------------------------------------------------------------------
__global__ __launch_bounds__(256)
void bucket_gather_kernel(const u16* __restrict__ FW,
                          const int* __restrict__ cnts,
                          const u32* __restrict__ csr,
                          const float* __restrict__ b,
                          float* __restrict__ out) {
    __shared__ u16 srt[kRawMax];
    __shared__ int cnt8[8], noff8[8], cur8[8];
    int t   = threadIdx.x;
    int bkt = blockIdx.x;

    int myLen = (t < kNCHUNK) ? cnts[t * kNB + bkt] : 0;
    if (t < 8) cnt8[t] = 0;

    // --- load sub-run into registers (4 x uint4 = 64B line, coalesced) ---
    uint4 rec[4];
    const u32* sr = csr + ((size_t)bkt * kNCHUNK + t) * kCap;
#pragma unroll
    for (int i = 0; i < 4; ++i) {
        if (i * 4 < myLen) rec[i] = *reinterpret_cast<const uint4*>(sr + i * 4);
    }
    __syncthreads();   // cnt8 init visible

    // --- count pass ---
#pragma unroll
    for (int i = 0; i < 4; ++i) {
        if (i * 4 < myLen) {
            atomicAdd(&cnt8[(rec[i].x >> 16) & 7], 1);
            if (i * 4 + 1 < myLen) atomicAdd(&cnt8[(rec[i].y >> 16) & 7], 1);
            if (i * 4 + 2 < myLen) atomicAdd(&cnt8[(rec[i].z >> 16) & 7], 1);
            if (i * 4 + 3 < myLen) atomicAdd(&cnt8[(rec[i].w >> 16) & 7], 1);
        }
    }
    __syncthreads();
    if (t == 0) {
        int r = 0;
#pragma unroll
        for (int i = 0; i < 8; ++i) { noff8[i] = r; cur8[i] = r; r += cnt8[i]; }
    }
    __syncthreads();

    // --- scatter pass: registers -> sorted LDS positions ---
#pragma unroll
    for (int i = 0; i < 4; ++i) {
        if (i * 4 < myLen) {
            int p;
            p = atomicAdd(&cur8[(rec[i].x >> 16) & 7], 1);
            if (p < kRawMax) srt[p] = (u16)(rec[i].x & 0xFFFFu);
            if (i * 4 + 1 < myLen) {
                p = atomicAdd(&cur8[(rec[i].y >> 16) & 7], 1);
                if (p < kRawMax) srt[p] = (u16)(rec[i].y & 0xFFFFu);
            }
            if (i * 4 + 2 < myLen) {
                p = atomicAdd(&cur8[(rec[i].z >> 16) & 7], 1);
                if (p < kRawMax) srt[p] = (u16)(rec[i].z & 0xFFFFu);
            }
            if (i * 4 + 3 < myLen) {
                p = atomicAdd(&cur8[(rec[i].w >> 16) & 7], 1);
                if (p < kRawMax) srt[p] = (u16)(rec[i].w & 0xFFFFu);
            }
        }
    }
    __syncthreads();

    // --- per-node gather: 4 waves x 2 nodes (32-lane halves), uint2/lane ---
    int wv     = t >> 6;
    int lane   = t & 63;
    int half   = lane >> 5;
    int lane32 = lane & 31;
    int nodeBase = bkt * 8;
    const float4 bb = *reinterpret_cast<const float4*>(b + lane32 * 4);

    {
        int nd   = wv * 2 + half;              // 4 waves x 2 halves = 8 nodes
        int node = nodeBase + nd;
        int s0 = noff8[nd];
        int e0 = s0 + cnt8[nd];
        if (e0 > kRawMax) e0 = kRawMax;
        float ax = 0.f, ay = 0.f, az = 0.f, aw = 0.f;
        int i = s0;
        for (; i + 8 <= e0; i += 8) {
            uint2 v[8];
#pragma unroll
            for (int u = 0; u < 8; ++u) {
                int s = (int)srt[i + u];     // LDS broadcast within half
                v[u] = *reinterpret_cast<const uint2*>(FW + (size_t)s * kD + lane32 * 4);
            }
#pragma unroll
            for (int u = 0; u < 8; ++u) {
                ax += bf_lo(v[u].x); ay += bf_hi(v[u].x);
                az += bf_lo(v[u].y); aw += bf_hi(v[u].y);
            }
        }
        for (; i < e0; ++i) {
            int s = (int)srt[i];
            uint2 v = *reinterpret_cast<const uint2*>(FW + (size_t)s * kD + lane32 * 4);
            ax += bf_lo(v.x); ay += bf_hi(v.x);
            az += bf_lo(v.y); aw += bf_hi(v.y);
        }
        *reinterpret_cast<float4*>(out + (size_t)node * kD + lane32 * 4) =
            make_float4(ax + bb.x, ay + bb.y, az + bb.z, aw + bb.w);
    }
}

extern "C" void kernel_launch(void* const* d_in, const int* in_sizes, int n_in,
                              void* d_out, int out_size, void* d_ws, size_t ws_size,
                              hipStream_t stream) {
    const float* feature = (const float*)d_in[0];
    const int*   src     = (const int*)d_in[1];
    const int*   dst     = (const int*)d_in[2];
    const float* W       = (const float*)d_in[3];
    const float* b       = (const float*)d_in[4];
    float*       out     = (float*)d_out;

    // Workspace layout (Path B) — fully rewritten each call, no init needed
    //   FW   : kNodes*kD u16                    (2,560,000 B)
    //   cnts : kNCHUNK*kNB int                  (1,250,000 B)
    //   csr  : kNB*kNCHUNK*kCap u32             (20,000,000 B), 128B-aligned
    char* ws = (char*)d_ws;
    size_t off = 0;
    u16* FW   = (u16*)(ws + off);  off += (size_t)kNodes * kD * sizeof(u16);
    int* cnts = (int*)(ws + off);  off += (size_t)kNCHUNK * kNB * sizeof(int);
    off = (off + 127) & ~(size_t)127;
    u32* csr  = (u32*)(ws + off);  off += (size_t)kNB * kNCHUNK * kCap * sizeof(u32);
    const size_t neededB = off;
    const size_t neededA = (size_t)kNodes * kD * sizeof(float);

    if (ws_size >= neededB) {
        phase1_kernel<<<kNCHUNK + kGemmBlocks, 256, 0, stream>>>(
            feature, W, src, dst, FW, cnts, csr);
        bucket_gather_kernel<<<kNB, 256, 0, stream>>>(FW, cnts, csr, b, out);
    } else if (ws_size >= neededA) {
        float* h = (float*)d_ws;
        hipMemsetAsync(h, 0, neededA, stream);
        long long total = (long long)kEdges * 32;
        int threads = 256;
        int blocks  = (int)((total + threads - 1) / threads);
        scatter_add_kernel<<<blocks, threads, 0, stream>>>(feature, src, dst, h);
        gemm_bias_kernel<<<(kNodes + 7) / 8, 256, 0, stream>>>(h, W, b, out);
    }
}

// Round 20
// 38.689 us; speedup vs baseline: 1.1441x; 1.0110x over previous
//
#include <hip/hip_runtime.h>

constexpr int kNodes = 10000;
constexpr int kEdges = 640000;
constexpr int kD = 128;

typedef unsigned int   u32;
typedef unsigned short u16;

constexpr int kNB     = 1250;                 // buckets of 8 nodes (10000/8)
constexpr int kNCHUNK = 250;                  // partition blocks
constexpr int kCHUNK  = 2560;                 // edges per partition block
constexpr int kCap    = 16;                   // per-(blk,bkt) sub-run capacity (mean 2.05)
constexpr int kRawMax = 1024;                 // per-bucket edge cap (mean 512, +22 sigma)
constexpr int kGemmBlocks = kNodes / 16;      // 625 (16 rows per block)

__device__ inline u16 f2bf(float x) {         // round-to-nearest-even
    u32 u = __float_as_uint(x);
    u32 r = u + 0x7FFF + ((u >> 16) & 1);
    return (u16)(r >> 16);
}
__device__ inline float bf_lo(u32 v) { return __uint_as_float(v << 16); }
__device__ inline float bf_hi(u32 v) { return __uint_as_float(v & 0xFFFF0000u); }

// ---------------------------------------------------------------------------
// Path A (fallback): direct atomic scatter-add + fp32 GEMM
// ---------------------------------------------------------------------------
__global__ void scatter_add_kernel(const float* __restrict__ feature,
                                   const int* __restrict__ src,
                                   const int* __restrict__ dst,
                                   float* __restrict__ h) {
    long long tid = (long long)blockIdx.x * blockDim.x + threadIdx.x;
    int e    = (int)(tid >> 5);
    int lane = (int)(tid & 31);
    if (e >= kEdges) return;
    int s = src[e];
    int d = dst[e];
    const float4 v = *reinterpret_cast<const float4*>(feature + (size_t)s * kD + lane * 4);
    float* hp = h + (size_t)d * kD + lane * 4;
    atomicAdd(hp + 0, v.x);
    atomicAdd(hp + 1, v.y);
    atomicAdd(hp + 2, v.z);
    atomicAdd(hp + 3, v.w);
}

__global__ __launch_bounds__(256)
void gemm_bias_kernel(const float* __restrict__ h,
                      const float* __restrict__ W,
                      const float* __restrict__ b,
                      float* __restrict__ out) {
    __shared__ float Wl[kD * kD];
    int t = threadIdx.x;
#pragma unroll
    for (int i = 0; i < 16; ++i) {
        int idx = t + i * 256;
        reinterpret_cast<float4*>(Wl)[idx] = reinterpret_cast<const float4*>(W)[idx];
    }
    __syncthreads();
    int row = blockIdx.x * 8 + (t >> 5);
    int j0  = (t & 31) * 4;
    if (row >= kNodes) return;
    const float* hrow = h + (size_t)row * kD;
    float4 acc = make_float4(0.f, 0.f, 0.f, 0.f);
#pragma unroll 4
    for (int k = 0; k < kD; k += 4) {
        float4 hv4 = *reinterpret_cast<const float4*>(hrow + k);
        const float* wk = Wl + (size_t)k * kD + j0;
        float4 w0 = *reinterpret_cast<const float4*>(wk + 0 * kD);
        float4 w1 = *reinterpret_cast<const float4*>(wk + 1 * kD);
        float4 w2 = *reinterpret_cast<const float4*>(wk + 2 * kD);
        float4 w3 = *reinterpret_cast<const float4*>(wk + 3 * kD);
        acc.x += hv4.x * w0.x + hv4.y * w1.x + hv4.z * w2.x + hv4.w * w3.x;
        acc.y += hv4.x * w0.y + hv4.y * w1.y + hv4.z * w2.y + hv4.w * w3.y;
        acc.z += hv4.x * w0.z + hv4.y * w1.z + hv4.z * w2.z + hv4.w * w3.z;
        acc.w += hv4.x * w0.w + hv4.y * w1.w + hv4.z * w2.w + hv4.w * w3.w;
    }
    const float4 bb = *reinterpret_cast<const float4*>(b + j0);
    acc.x += bb.x; acc.y += bb.y; acc.z += bb.z; acc.w += bb.w;
    *reinterpret_cast<float4*>(out + (size_t)row * kD + j0) = acc;
}

// ---------------------------------------------------------------------------
// Path B, phase 1 (fused): blocks [0,250) partition edges into
// per-(bucket,block) sub-runs — csr laid out [bkt][blk][kCap] so the gather
// reads it coalesced; each 64B line still written by exactly one block.
// Blocks [250,875): 16 rows of FW = feature @ W (bf16 out), fp32 W staged
// in TWO 32 KB halves (k-split) -> 5 blocks/CU, all co-resident.
// (byte-identical to round 19)
// ---------------------------------------------------------------------------
__global__ __launch_bounds__(256)
void phase1_kernel(const float* __restrict__ feature,
                   const float* __restrict__ W,
                   const int* __restrict__ src,
                   const int* __restrict__ dst,
                   u16* __restrict__ FW,
                   int* __restrict__ cnts,     // [kNCHUNK][kNB]  (block-local writes)
                   u32* __restrict__ csr) {    // [kNB][kNCHUNK][kCap] (transposed)
    __shared__ float Wl[64 * kD];   // 32 KB; partition branch reuses 5 KB
    int t = threadIdx.x;

    if (blockIdx.x < kNCHUNK) {
        // ----- partition branch: single pass, LDS cursors only -----
        int* cur = reinterpret_cast<int*>(Wl);         // [kNB], 5 KB
        int blk  = blockIdx.x;

        for (int i = t; i < kNB; i += 256) cur[i] = 0;
        __syncthreads();

        int base = blk * kCHUNK;
#pragma unroll
        for (int j = 0; j < 10; ++j) {
            int e = base + t + j * 256;
            int d = dst[e];
            int s = src[e];
            int bkt = d >> 3;
            int pos = atomicAdd(&cur[bkt], 1);
            if (pos < kCap)
                csr[((size_t)bkt * kNCHUNK + blk) * kCap + pos] = ((u32)d << 16) | (u32)s;
        }
        __syncthreads();
        for (int i = t; i < kNB; i += 256) {
            int c = cur[i];
            cnts[blk * kNB + i] = c < kCap ? c : kCap;
        }
    } else {
        // ----- GEMM branch: 16 rows, 2 rows/thread, W in 2 half-stages -----
        int rp   = t >> 5;
        int j0   = (t & 31) * 4;
        int row0 = (blockIdx.x - kNCHUNK) * 16 + rp * 2;
        const float* h0 = feature + (size_t)row0 * kD;
        const float* h1 = h0 + kD;

        float4 acc0 = make_float4(0.f, 0.f, 0.f, 0.f);
        float4 acc1 = make_float4(0.f, 0.f, 0.f, 0.f);

        for (int kh = 0; kh < 2; ++kh) {
            const float4* Wsrc = reinterpret_cast<const float4*>(W + (size_t)kh * 64 * kD);
#pragma unroll
            for (int i = 0; i < 8; ++i) {
                int idx = t + i * 256;
                reinterpret_cast<float4*>(Wl)[idx] = Wsrc[idx];
            }
            __syncthreads();

            const float* ha0 = h0 + kh * 64;
            const float* ha1 = h1 + kh * 64;
#pragma unroll 4
            for (int k = 0; k < 64; k += 4) {
                float4 a0 = *reinterpret_cast<const float4*>(ha0 + k);
                float4 a1 = *reinterpret_cast<const float4*>(ha1 + k);
                const float* wk = Wl + (size_t)k * kD + j0;
                float4 w0 = *reinterpret_cast<const float4*>(wk + 0 * kD);
                float4 w1 = *reinterpret_cast<const float4*>(wk + 1 * kD);
                float4 w2 = *reinterpret_cast<const float4*>(wk + 2 * kD);
                float4 w3 = *reinterpret_cast<const float4*>(wk + 3 * kD);
                acc0.x += a0.x * w0.x + a0.y * w1.x + a0.z * w2.x + a0.w * w3.x;
                acc0.y += a0.x * w0.y + a0.y * w1.y + a0.z * w2.y + a0.w * w3.y;
                acc0.z += a0.x * w0.z + a0.y * w1.z + a0.z * w2.z + a0.w * w3.z;
                acc0.w += a0.x * w0.w + a0.y * w1.w + a0.z * w2.w + a0.w * w3.w;
                acc1.x += a1.x * w0.x + a1.y * w1.x + a1.z * w2.x + a1.w * w3.x;
                acc1.y += a1.x * w0.y + a1.y * w1.y + a1.z * w2.y + a1.w * w3.y;
                acc1.z += a1.x * w0.z + a1.y * w1.z + a1.z * w2.z + a1.w * w3.z;
                acc1.w += a1.x * w0.w + a1.y * w1.w + a1.z * w2.w + a1.w * w3.w;
            }
            if (kh == 0) __syncthreads();   // protect Wl before re-stage
        }

        u32 lo0 = (u32)f2bf(acc0.x) | ((u32)f2bf(acc0.y) << 16);
        u32 hi0 = (u32)f2bf(acc0.z) | ((u32)f2bf(acc0.w) << 16);
        u32 lo1 = (u32)f2bf(acc1.x) | ((u32)f2bf(acc1.y) << 16);
        u32 hi1 = (u32)f2bf(acc1.z) | ((u32)f2bf(acc1.w) << 16);
        *reinterpret_cast<uint2*>(FW + (size_t)row0 * kD + j0)       = make_uint2(lo0, hi0);
        *reinterpret_cast<uint2*>(FW + (size_t)(row0 + 1) * kD + j0) = make_uint2(lo1, hi1);
    }
}

// ---------------------------------------------------------------------------
// Path B, phase 2: one block per 8-node bucket (1250 blocks x 256 thr).
// NEW: unconditional 64B csr sub-run load — independent of the cnts load,
// so the two preamble memory rounds overlap instead of serializing.
// Stale tail slots are ignored via myLen guards in count/scatter passes.
// ---------------------------------------------------------------------------
__global__ __launch_bounds__(256)
void bucket_gather_kernel(const u16* __restrict__ FW,
                          const int* __restrict__ cnts,
                          const u32* __restrict__ csr,
                          const float* __restrict__ b,
                          float* __restrict__ out) {
    __shared__ u16 srt[kRawMax];
    __shared__ int cnt8[8], noff8[8], cur8[8];
    int t   = threadIdx.x;
    int bkt = blockIdx.x;

    // --- issue both loads back-to-back (independent) ---
    int tc = t < kNCHUNK ? t : 0;                      // clamp for csr addr
    const u32* sr = csr + ((size_t)bkt * kNCHUNK + tc) * kCap;
    uint4 rec[4];
#pragma unroll
    for (int i = 0; i < 4; ++i) {
        rec[i] = *reinterpret_cast<const uint4*>(sr + i * 4);   // full 64B line
    }
    int myLen = (t < kNCHUNK) ? cnts[t * kNB + bkt] : 0;

    if (t < 8) cnt8[t] = 0;
    __syncthreads();   // cnt8 init visible

    // --- count pass (myLen-guarded) ---
#pragma unroll
    for (int i = 0; i < 4; ++i) {
        if (i * 4 < myLen) {
            atomicAdd(&cnt8[(rec[i].x >> 16) & 7], 1);
            if (i * 4 + 1 < myLen) atomicAdd(&cnt8[(rec[i].y >> 16) & 7], 1);
            if (i * 4 + 2 < myLen) atomicAdd(&cnt8[(rec[i].z >> 16) & 7], 1);
            if (i * 4 + 3 < myLen) atomicAdd(&cnt8[(rec[i].w >> 16) & 7], 1);
        }
    }
    __syncthreads();
    if (t == 0) {
        int r = 0;
#pragma unroll
        for (int i = 0; i < 8; ++i) { noff8[i] = r; cur8[i] = r; r += cnt8[i]; }
    }
    __syncthreads();

    // --- scatter pass: registers -> sorted LDS positions ---
#pragma unroll
    for (int i = 0; i < 4; ++i) {
        if (i * 4 < myLen) {
            int p;
            p = atomicAdd(&cur8[(rec[i].x >> 16) & 7], 1);
            if (p < kRawMax) srt[p] = (u16)(rec[i].x & 0xFFFFu);
            if (i * 4 + 1 < myLen) {
                p = atomicAdd(&cur8[(rec[i].y >> 16) & 7], 1);
                if (p < kRawMax) srt[p] = (u16)(rec[i].y & 0xFFFFu);
            }
            if (i * 4 + 2 < myLen) {
                p = atomicAdd(&cur8[(rec[i].z >> 16) & 7], 1);
                if (p < kRawMax) srt[p] = (u16)(rec[i].z & 0xFFFFu);
            }
            if (i * 4 + 3 < myLen) {
                p = atomicAdd(&cur8[(rec[i].w >> 16) & 7], 1);
                if (p < kRawMax) srt[p] = (u16)(rec[i].w & 0xFFFFu);
            }
        }
    }
    __syncthreads();

    // --- per-node gather: 4 waves x 2 nodes (32-lane halves), uint2/lane ---
    int wv     = t >> 6;
    int lane   = t & 63;
    int half   = lane >> 5;
    int lane32 = lane & 31;
    int nodeBase = bkt * 8;
    const float4 bb = *reinterpret_cast<const float4*>(b + lane32 * 4);

    {
        int nd   = wv * 2 + half;              // 4 waves x 2 halves = 8 nodes
        int node = nodeBase + nd;
        int s0 = noff8[nd];
        int e0 = s0 + cnt8[nd];
        if (e0 > kRawMax) e0 = kRawMax;
        float ax = 0.f, ay = 0.f, az = 0.f, aw = 0.f;
        int i = s0;
        for (; i + 8 <= e0; i += 8) {
            uint2 v[8];
#pragma unroll
            for (int u = 0; u < 8; ++u) {
                int s = (int)srt[i + u];     // LDS broadcast within half
                v[u] = *reinterpret_cast<const uint2*>(FW + (size_t)s * kD + lane32 * 4);
            }
#pragma unroll
            for (int u = 0; u < 8; ++u) {
                ax += bf_lo(v[u].x); ay += bf_hi(v[u].x);
                az += bf_lo(v[u].y); aw += bf_hi(v[u].y);
            }
        }
        for (; i < e0; ++i) {
            int s = (int)srt[i];
            uint2 v = *reinterpret_cast<const uint2*>(FW + (size_t)s * kD + lane32 * 4);
            ax += bf_lo(v.x); ay += bf_hi(v.x);
            az += bf_lo(v.y); aw += bf_hi(v.y);
        }
        *reinterpret_cast<float4*>(out + (size_t)node * kD + lane32 * 4) =
            make_float4(ax + bb.x, ay + bb.y, az + bb.z, aw + bb.w);
    }
}

extern "C" void kernel_launch(void* const* d_in, const int* in_sizes, int n_in,
                              void* d_out, int out_size, void* d_ws, size_t ws_size,
                              hipStream_t stream) {
    const float* feature = (const float*)d_in[0];
    const int*   src     = (const int*)d_in[1];
    const int*   dst     = (const int*)d_in[2];
    const float* W       = (const float*)d_in[3];
    const float* b       = (const float*)d_in[4];
    float*       out     = (float*)d_out;

    // Workspace layout (Path B) — fully rewritten each call, no init needed
    //   FW   : kNodes*kD u16                    (2,560,000 B)
    //   cnts : kNCHUNK*kNB int                  (1,250,000 B)
    //   csr  : kNB*kNCHUNK*kCap u32             (20,000,000 B), 128B-aligned
    char* ws = (char*)d_ws;
    size_t off = 0;
    u16* FW   = (u16*)(ws + off);  off += (size_t)kNodes * kD * sizeof(u16);
    int* cnts = (int*)(ws + off);  off += (size_t)kNCHUNK * kNB * sizeof(int);
    off = (off + 127) & ~(size_t)127;
    u32* csr  = (u32*)(ws + off);  off += (size_t)kNB * kNCHUNK * kCap * sizeof(u32);
    const size_t neededB = off;
    const size_t neededA = (size_t)kNodes * kD * sizeof(float);

    if (ws_size >= neededB) {
        phase1_kernel<<<kNCHUNK + kGemmBlocks, 256, 0, stream>>>(
            feature, W, src, dst, FW, cnts, csr);
        bucket_gather_kernel<<<kNB, 256, 0, stream>>>(FW, cnts, csr, b, out);
    } else if (ws_size >= neededA) {
        float* h = (float*)d_ws;
        hipMemsetAsync(h, 0, neededA, stream);
        long long total = (long long)kEdges * 32;
        int threads = 256;
        int blocks  = (int)((total + threads - 1) / threads);
        scatter_add_kernel<<<blocks, threads, 0, stream>>>(feature, src, dst, h);
        gemm_bias_kernel<<<(kNodes + 7) / 8, 256, 0, stream>>>(h, W, b, out);
    }
}